// Round 4
// baseline (1077.072 us; speedup 1.0000x reference)
//
#include <hip/hip_runtime.h>
#include <hip/hip_bf16.h>

// ---------------------------------------------------------------------------
// Encoder block. B=8, N=128, DIM=256, HEADS=8, dk=32, HID=1024.
// R7: k_mlp_y6 = 4-wave block (256 thr, 128 rows). An 8-wave block forces
// >=2 waves/SIMD -> 256-reg unified ceiling -> R5/R6 spilled (~78MB scratch
// writeback, VGPR stuck at 128). 4 waves on 4 SIMDs allows 1 wave/SIMD ->
// 512-reg ceiling; demand ~250 fits with 2x headroom. Same per-wave tile
// (32 rows, 32x32x16 MFMA, dbuf global_load_lds weight staging).
// LDS 144 KiB, grid 1024.
// ---------------------------------------------------------------------------

#define DIMC 256
#define NSEQ 128
#define NB 8
#define HID 1024
#define EROWS (NB * NSEQ * NSEQ)   // 131072

typedef __attribute__((ext_vector_type(8)))  short short8;
typedef __attribute__((ext_vector_type(16))) float f32x16;
typedef __attribute__((ext_vector_type(4)))  float f32x4;

__device__ __forceinline__ short f2bf(float f) {
    union { float f; unsigned u; } v; v.f = f;
    unsigned r = (v.u + 0x7FFF + ((v.u >> 16) & 1)) >> 16;
    return (short)r;
}
__device__ __forceinline__ float bf2f(short s) {
    union { unsigned u; float f; } v; v.u = ((unsigned)(unsigned short)s) << 16;
    return v.f;
}

__device__ __forceinline__ float wave_sum(float v) {
    #pragma unroll
    for (int o = 32; o; o >>= 1) v += __shfl_xor(v, o, 64);
    return v;
}

__device__ __forceinline__ float block_reduce_sum(float v, float* sc, int t) {
    #pragma unroll
    for (int o = 32; o > 0; o >>= 1) v += __shfl_down(v, o, 64);
    __syncthreads();
    if ((t & 63) == 0) sc[t >> 6] = v;
    __syncthreads();
    return sc[0] + sc[1] + sc[2] + sc[3];
}

// ---------------------------------------------------------------------------
// Kernel 1: x1 = LN1(x); q/k/v = x1 @ W{q,k,v} + b.  One block per (b,i) row.
// ---------------------------------------------------------------------------
__global__ __launch_bounds__(256, 2) void k_ln_qkv(
    const float* __restrict__ X, const float* __restrict__ g, const float* __restrict__ be,
    const float* __restrict__ Wq, const float* __restrict__ bq,
    const float* __restrict__ Wk, const float* __restrict__ bk,
    const float* __restrict__ Wv, const float* __restrict__ bv,
    float* __restrict__ X1, float* __restrict__ Q, float* __restrict__ K, float* __restrict__ V)
{
    __shared__ float xs[DIMC];
    __shared__ float red[4];
    const int t = threadIdx.x;
    const int row = blockIdx.x;
    float v = X[(size_t)row * DIMC + t];
    float mu = block_reduce_sum(v, red, t) * (1.f / DIMC);
    float d = v - mu;
    float var = block_reduce_sum(d * d, red, t) * (1.f / DIMC);
    float x1v = d * rsqrtf(var + 1e-5f) * g[t] + be[t];
    xs[t] = x1v;
    X1[(size_t)row * DIMC + t] = x1v;
    __syncthreads();
    float aq = bq[t], ak = bk[t], av = bv[t];
    #pragma unroll 4
    for (int k2 = 0; k2 < DIMC; ++k2) {
        float xv = xs[k2];
        aq = fmaf(xv, Wq[k2 * DIMC + t], aq);
        ak = fmaf(xv, Wk[k2 * DIMC + t], ak);
        av = fmaf(xv, Wv[k2 * DIMC + t], av);
    }
    Q[(size_t)row * DIMC + t] = aq;
    K[(size_t)row * DIMC + t] = ak;
    V[(size_t)row * DIMC + t] = av;
}

// ---------------------------------------------------------------------------
// Transpose + fp32->bf16 convert: dst[N][M] = bf16(src[M][N]).
// ---------------------------------------------------------------------------
__global__ __launch_bounds__(256) void k_transpose_bf16(
    const float* __restrict__ src, short* __restrict__ dst, int M, int N)
{
    __shared__ short tile[32][33];
    const int t = threadIdx.x, tx = t & 31, ty = t >> 5;
    const int bx = blockIdx.x, by = blockIdx.y;
    #pragma unroll
    for (int r = ty; r < 32; r += 8)
        tile[r][tx] = f2bf(src[(size_t)(by * 32 + r) * N + bx * 32 + tx]);
    __syncthreads();
    #pragma unroll
    for (int r = ty; r < 32; r += 8)
        dst[(size_t)(bx * 32 + r) * M + by * 32 + tx] = tile[tx][r];
}

// ---------------------------------------------------------------------------
// k_prep_wc: pack m2_W1/m2_W2 into chunk-major, swizzled bf16 layout.
// ---------------------------------------------------------------------------
__global__ __launch_bounds__(256) void k_prep_wc(
    const float* __restrict__ W1, const float* __restrict__ W2, short* __restrict__ Wc)
{
    const int h = blockIdx.x, t = threadIdx.x;
    short* dst = Wc + (size_t)h * 32768;
    const int hh = t & 63, kq = t >> 6;
    for (int k0 = 0; k0 < 256; k0 += 4) {
        const int k = k0 + kq;
        float v = W1[(size_t)k * HID + h * 64 + hh];
        dst[hh * 256 + (((k >> 3) ^ (hh & 7)) << 3) + (k & 7)] = f2bf(v);
    }
    short* dst2 = dst + 16384;
    for (int kk = 0; kk < 64; ++kk) {
        float v = W2[(size_t)(h * 64 + kk) * DIMC + t];
        dst2[t * 64 + (((kk >> 3) ^ (t & 7)) << 3) + (kk & 7)] = f2bf(v);
    }
}

// ---------------------------------------------------------------------------
// k_e_attn_m: e = Y @ We + be (bf16 MFMA, 64 rows x 256 cols per block);
// epilogue: attn = (q*k/sqrt(32))*(e+1)*e -> ATTb (bf16).
// ---------------------------------------------------------------------------
__global__ __launch_bounds__(256, 2) void k_e_attn_m(
    const float* __restrict__ Y, const short* __restrict__ WeT,
    const float* __restrict__ be,
    const float* __restrict__ Q, const float* __restrict__ Kp,
    short* __restrict__ ATTb)
{
    __shared__ __align__(16) short As[64][256];
    const int t = threadIdx.x, w = t >> 6, lane = t & 63;
    const int l31 = lane & 31, kg = lane >> 5;
    const size_t R0 = (size_t)blockIdx.x * 64;

    for (int r = w * 16; r < w * 16 + 16; ++r) {
        float4 y4 = *(const float4*)&Y[(R0 + r) * DIMC + lane * 4];
        short4 s4;
        s4.x = f2bf(y4.x); s4.y = f2bf(y4.y); s4.z = f2bf(y4.z); s4.w = f2bf(y4.w);
        *(short4*)&As[r][(((lane >> 1) ^ (r & 7)) << 3) + (lane & 1) * 4] = s4;
    }
    __syncthreads();

    const int rh = (w & 1) * 32, cbase = (w >> 1) * 128;
    const int sw = l31 & 7;
    f32x16 acc[4];
    #pragma unroll
    for (int a = 0; a < 4; ++a)
        #pragma unroll
        for (int i = 0; i < 16; ++i) acc[a][i] = 0.f;

    #pragma unroll
    for (int ks = 0; ks < 16; ++ks) {
        const int gk = 2 * ks + kg;
        short8 a = *(const short8*)&As[rh + l31][(gk ^ sw) * 8];
        #pragma unroll
        for (int tt = 0; tt < 4; ++tt) {
            short8 b = *(const short8*)&WeT[(size_t)(cbase + tt * 32 + l31) * DIMC + gk * 8];
            acc[tt] = __builtin_amdgcn_mfma_f32_32x32x16_bf16(a, b, acc[tt], 0, 0, 0);
        }
    }

    const int m0 = (int)(R0);
    const int qrow = m0 >> 7, bidx = m0 >> 14, jb = m0 & 127;
    const float isq = 0.17677669529663687f;   // 1/sqrt(32)
    #pragma unroll
    for (int tt = 0; tt < 4; ++tt) {
        const int n = cbase + tt * 32 + l31;
        const float qv = Q[(size_t)qrow * DIMC + n];
        const float bb = be[n];
        #pragma unroll
        for (int i = 0; i < 16; ++i) {
            const int row = rh + 4 * kg + (i & 3) + 8 * (i >> 2);
            const float kv = Kp[(size_t)((bidx << 7) + jb + row) * DIMC + n];
            const float e = acc[tt][i] + bb;
            const float qk = qv * kv * isq;
            ATTb[(size_t)(m0 + row) * DIMC + n] = f2bf(qk * (e + 1.f) * e);
        }
    }
}

// ---------------------------------------------------------------------------
// k_edge_m: edge = ATTb @ Woe + boe (bf16 MFMA) -> EY fp32 (d_out y-region).
// ---------------------------------------------------------------------------
__global__ __launch_bounds__(256, 2) void k_edge_m(
    const short* __restrict__ ATTb, const short* __restrict__ WoeT,
    const float* __restrict__ boe, float* __restrict__ EDGE)
{
    __shared__ __align__(16) short As[64][256];
    const int t = threadIdx.x, w = t >> 6, lane = t & 63;
    const int l31 = lane & 31, kg = lane >> 5;
    const size_t R0 = (size_t)blockIdx.x * 64;

    #pragma unroll
    for (int it = 0; it < 8; ++it) {
        const int r = w * 16 + it * 2 + kg;
        short8 v = *(const short8*)&ATTb[(R0 + r) * DIMC + l31 * 8];
        *(short8*)&As[r][((l31 ^ (r & 7))) * 8] = v;
    }
    __syncthreads();

    const int rh = (w & 1) * 32, cbase = (w >> 1) * 128;
    const int sw = l31 & 7;
    f32x16 acc[4];
    #pragma unroll
    for (int a = 0; a < 4; ++a)
        #pragma unroll
        for (int i = 0; i < 16; ++i) acc[a][i] = 0.f;

    #pragma unroll
    for (int ks = 0; ks < 16; ++ks) {
        const int gk = 2 * ks + kg;
        short8 a = *(const short8*)&As[rh + l31][(gk ^ sw) * 8];
        #pragma unroll
        for (int tt = 0; tt < 4; ++tt) {
            short8 b = *(const short8*)&WoeT[(size_t)(cbase + tt * 32 + l31) * DIMC + gk * 8];
            acc[tt] = __builtin_amdgcn_mfma_f32_32x32x16_bf16(a, b, acc[tt], 0, 0, 0);
        }
    }

    const int m0 = (int)(R0);
    #pragma unroll
    for (int tt = 0; tt < 4; ++tt) {
        const int n = cbase + tt * 32 + l31;
        const float bb = boe[n];
        #pragma unroll
        for (int i = 0; i < 16; ++i) {
            const int row = rh + 4 * kg + (i & 3) + 8 * (i >> 2);
            EDGE[(size_t)(m0 + row) * DIMC + n] = acc[tt][i] + bb;
        }
    }
}

// ---------------------------------------------------------------------------
// Kernel 4: x-path tail. ATT bf16. Max-free softmax (logits tiny, exp safe).
// ---------------------------------------------------------------------------
__global__ __launch_bounds__(256, 2) void k_node_x(
    const short* __restrict__ ATTb, const float* __restrict__ V,
    const float* __restrict__ X1,
    const float* __restrict__ Won, const float* __restrict__ bon,
    const float* __restrict__ g3, const float* __restrict__ b3,
    const float* __restrict__ W1, const float* __restrict__ b1,
    const float* __restrict__ W2, const float* __restrict__ b2,
    const float* __restrict__ g5, const float* __restrict__ b5,
    float* __restrict__ OUTX)
{
    __shared__ float ns[DIMC];
    __shared__ float x2s[DIMC];
    __shared__ float hs[HID];
    __shared__ float red[4];
    const int t = threadIdx.x;
    const int bi = blockIdx.x;
    const int b = bi >> 7;
    const short* arow = ATTb + (size_t)bi * NSEQ * DIMC + t;
    const float* vbase = V + (size_t)b * NSEQ * DIMC + t;
    float l = 0.f, acc = 0.f;
    #pragma unroll 4
    for (int j = 0; j < NSEQ; ++j) {
        float a = bf2f(arow[(size_t)j * DIMC]);
        float vv = vbase[(size_t)j * DIMC];
        float p = __expf(a);
        l += p;
        acc = fmaf(p, vv, acc);
    }
    ns[t] = acc / l;
    __syncthreads();
    float o = bon[t];
    #pragma unroll 4
    for (int k2 = 0; k2 < DIMC; ++k2) o = fmaf(ns[k2], Won[k2 * DIMC + t], o);
    float resid = X1[(size_t)bi * DIMC + t] + o;
    float mu = block_reduce_sum(resid, red, t) * (1.f / DIMC);
    float d = resid - mu;
    float var = block_reduce_sum(d * d, red, t) * (1.f / DIMC);
    float x2 = d * rsqrtf(var + 1e-5f) * g3[t] + b3[t];
    x2s[t] = x2;
    __syncthreads();
    float4 h = *(const float4*)&b1[t * 4];
    for (int k2 = 0; k2 < DIMC; ++k2) {
        float xv = x2s[k2];
        float4 w = *(const float4*)&W1[(size_t)k2 * HID + t * 4];
        h.x = fmaf(xv, w.x, h.x); h.y = fmaf(xv, w.y, h.y);
        h.z = fmaf(xv, w.z, h.z); h.w = fmaf(xv, w.w, h.w);
    }
    h.x = fmaxf(h.x, 0.f); h.y = fmaxf(h.y, 0.f); h.z = fmaxf(h.z, 0.f); h.w = fmaxf(h.w, 0.f);
    *(float4*)&hs[t * 4] = h;
    __syncthreads();
    float o2 = b2[t];
    #pragma unroll 4
    for (int hh = 0; hh < HID; ++hh) o2 = fmaf(hs[hh], W2[(size_t)hh * DIMC + t], o2);
    float r2 = x2 + o2;
    float mu2 = block_reduce_sum(r2, red, t) * (1.f / DIMC);
    float d2 = r2 - mu2;
    float v2 = block_reduce_sum(d2 * d2, red, t) * (1.f / DIMC);
    OUTX[(size_t)bi * DIMC + t] = d2 * rsqrtf(v2 + 1e-5f) * g5[t] + b5[t];
}

// ---------------------------------------------------------------------------
// Kernel 5 (R7): k_mlp_y6 — fused y-path tail.
// 128 rows/block, 4 waves x 32 rows, 32x32x16 bf16 MFMA, 256 threads.
// 1 wave/SIMD -> 512-reg ceiling -> no spill (demand ~250).
// Weight chunks double-buffered via global_load_lds; 1 barrier/chunk.
// LDS = 128K (Wbuf) + 16K (Hscr) = 144 KiB.
// ---------------------------------------------------------------------------
__global__ __launch_bounds__(256, 1) void k_mlp_y6(
    float* __restrict__ EY, const float* __restrict__ Y,
    const float* __restrict__ g4, const float* __restrict__ b4,
    const short* __restrict__ Wc, const float* __restrict__ b1v,
    const float* __restrict__ b2v,
    const float* __restrict__ g6, const float* __restrict__ b6)
{
    __shared__ __align__(16) short Wbuf[2][32768];   // 128 KB (buf0 also y2 staging)
    __shared__ __align__(16) short Hscr[4][32][64];  // 16 KB, XOR-swizzled
    const int t = threadIdx.x;
    const int w = t >> 6, lane = t & 63;
    const int l31 = lane & 31, kg = lane >> 5;
    const int r7 = l31 & 7;
    const size_t R0 = (size_t)blockIdx.x * 128;
    short* Wb = &Wbuf[0][0];   // flat 65536 shorts = 128 rows x 256 cols

    // --- Phase A: y2 = LN4(EY + Y), rows w*32..w*32+31 -> Wb (bf16, swizzled)
    {
        const float4 gv = *(const float4*)&g4[lane * 4];
        const float4 bv = *(const float4*)&b4[lane * 4];
        const int gw = lane >> 1;
        for (int rr = 0; rr < 32; ++rr) {
            const int row = w * 32 + rr;
            const float4 e4 = *(const float4*)&EY[(R0 + row) * DIMC + lane * 4];
            const float4 y4v = *(const float4*)&Y[(R0 + row) * DIMC + lane * 4];
            float v0 = e4.x + y4v.x, v1 = e4.y + y4v.y, v2 = e4.z + y4v.z, v3 = e4.w + y4v.w;
            float mu = wave_sum(v0 + v1 + v2 + v3) * (1.f / DIMC);
            float d0 = v0 - mu, d1 = v1 - mu, d2 = v2 - mu, d3 = v3 - mu;
            float var = wave_sum(d0 * d0 + d1 * d1 + d2 * d2 + d3 * d3) * (1.f / DIMC);
            float rs = rsqrtf(var + 1e-5f);
            short4 s4;
            s4.x = f2bf(d0 * rs * gv.x + bv.x);
            s4.y = f2bf(d1 * rs * gv.y + bv.y);
            s4.z = f2bf(d2 * rs * gv.z + bv.z);
            s4.w = f2bf(d3 * rs * gv.w + bv.w);
            *(short4*)&Wb[row * 256 + ((gw ^ (rr & 7)) << 3) + (lane & 1) * 4] = s4;
        }
    }
    // --- A-fragments: wave's 32 rows x K=256 (wave-local write->read, no barrier)
    short8 af[16];
    {
        const int row = w * 32 + l31;      // row & 7 == r7
        #pragma unroll
        for (int s = 0; s < 16; ++s)
            af[s] = *(const short8*)&Wb[row * 256 + (((2 * s + kg) ^ r7) << 3)];
    }

    // --- async stage: chunk h -> Wbuf[buf] (linear; 64 KB via 256 thr x 16 x 16B)
    auto stage = [&](int h, int buf) {
        const char* src = (const char*)Wc + (size_t)h * 65536 + t * 16;
        char* dstb = (char*)&Wbuf[buf][0] + t * 16;
        #pragma unroll
        for (int p = 0; p < 16; ++p) {
            __builtin_amdgcn_global_load_lds(
                (const __attribute__((address_space(1))) unsigned*)(src + p * 4096),
                (__attribute__((address_space(3))) unsigned*)(dstb + p * 4096),
                16, 0, 0);
        }
    };
    stage(0, 1);
    __syncthreads();   // drains vmcnt -> chunk 0 ready; af reads done block-wide

    f32x16 acc[8];
    #pragma unroll
    for (int a = 0; a < 8; ++a)
        #pragma unroll
        for (int i = 0; i < 16; ++i) acc[a][i] = 0.f;

    for (int h = 0; h < 16; ++h) {
        const short* Wlds = &Wbuf[1 - (h & 1)][0];
        if (h < 15) stage(h + 1, h & 1);
        const float bb0 = b1v[h * 64 + l31];
        const float bb1 = b1v[h * 64 + 32 + l31];

        // GEMM1: H(32x64) = y2(32x256) @ W1chunk(256x64)
        f32x16 c1[2];
        #pragma unroll
        for (int a = 0; a < 2; ++a)
            #pragma unroll
            for (int i = 0; i < 16; ++i) c1[a][i] = 0.f;
        #pragma unroll
        for (int s = 0; s < 16; ++s) {
            const int g = ((2 * s + kg) ^ r7) << 3;
            #pragma unroll
            for (int tt = 0; tt < 2; ++tt) {
                short8 b = *(const short8*)&Wlds[(tt * 32 + l31) * 256 + g];
                c1[tt] = __builtin_amdgcn_mfma_f32_32x32x16_bf16(af[s], b, c1[tt], 0, 0, 0);
            }
        }
        // relu + bias -> per-wave H scratch (C-frag: col=l31+32tt, row=4kg+(i&3)+8(i>>2))
        #pragma unroll
        for (int tt = 0; tt < 2; ++tt) {
            const int cq = tt * 4 + (l31 >> 3), c7 = l31 & 7;
            const float bb = tt ? bb1 : bb0;
            #pragma unroll
            for (int i = 0; i < 16; ++i) {
                const int row = 4 * kg + (i & 3) + 8 * (i >> 2);
                Hscr[w][row][((cq ^ (row & 7)) << 3) + c7] =
                    f2bf(fmaxf(c1[tt][i] + bb, 0.f));
            }
        }
        // GEMM2: acc(32x256) += H(32x64) @ W2chunk(64x256)
        #pragma unroll
        for (int s = 0; s < 4; ++s) {
            const int g2 = ((2 * s + kg) ^ r7) << 3;
            short8 hf = *(const short8*)&Hscr[w][l31][g2];
            #pragma unroll
            for (int ct = 0; ct < 8; ++ct) {
                short8 b = *(const short8*)&Wlds[16384 + (ct * 32 + l31) * 64 + g2];
                acc[ct] = __builtin_amdgcn_mfma_f32_32x32x16_bf16(hf, b, acc[ct], 0, 0, 0);
            }
        }
        __syncthreads();   // drains vmcnt (next chunk landed) + protects buffers
    }

    // --- Epilogue ---
    // re-materialize y2 (wave-local rows) into Wb for C-frag-layout residual read
    {
        const int row = w * 32 + l31;
        #pragma unroll
        for (int s = 0; s < 16; ++s)
            *(short8*)&Wb[row * 256 + (((2 * s + kg) ^ r7) << 3)] = af[s];
    }
    // residual + bias into acc
    #pragma unroll
    for (int ct = 0; ct < 8; ++ct) {
        const int col = ct * 32 + l31;
        const float bb = b2v[col];
        const int cq = col >> 3, c7 = col & 7;
        #pragma unroll
        for (int i = 0; i < 16; ++i) {
            const int row = 4 * kg + (i & 3) + 8 * (i >> 2);
            short yv = Wb[(w * 32 + row) * 256 + ((cq ^ (row & 7)) << 3) + c7];
            acc[ct][i] += bb + bf2f(yv);
        }
    }
    // LN6: per-row reduce over 8 col-tiles then 32 lanes (kg halves independent)
    float mus[16], rss[16];
    #pragma unroll
    for (int i = 0; i < 16; ++i) {
        float s = 0.f;
        #pragma unroll
        for (int ct = 0; ct < 8; ++ct) s += acc[ct][i];
        #pragma unroll
        for (int m = 1; m < 32; m <<= 1) s += __shfl_xor(s, m, 64);
        mus[i] = s * (1.f / DIMC);
    }
    #pragma unroll
    for (int i = 0; i < 16; ++i) {
        float v = 0.f;
        #pragma unroll
        for (int ct = 0; ct < 8; ++ct) { float d = acc[ct][i] - mus[i]; v += d * d; }
        #pragma unroll
        for (int m = 1; m < 32; m <<= 1) v += __shfl_xor(v, m, 64);
        rss[i] = rsqrtf(v * (1.f / DIMC) + 1e-5f);
    }
    #pragma unroll
    for (int ct = 0; ct < 8; ++ct) {
        const int col = ct * 32 + l31;
        const float gg = g6[col], bo = b6[col];
        #pragma unroll
        for (int i = 0; i < 16; ++i) {
            const int row = 4 * kg + (i & 3) + 8 * (i >> 2);
            EY[(R0 + w * 32 + row) * DIMC + col] = (acc[ct][i] - mus[i]) * rss[i] * gg + bo;
        }
    }
}

// ---------------------------------------------------------------------------
extern "C" void kernel_launch(void* const* d_in, const int* in_sizes, int n_in,
                              void* d_out, int out_size, void* d_ws, size_t ws_size,
                              hipStream_t stream) {
    const float* x    = (const float*)d_in[0];
    const float* y    = (const float*)d_in[1];
    const float* Wq   = (const float*)d_in[3];  const float* bq  = (const float*)d_in[4];
    const float* Wk   = (const float*)d_in[5];  const float* bk  = (const float*)d_in[6];
    const float* Wv   = (const float*)d_in[7];  const float* bv  = (const float*)d_in[8];
    const float* We   = (const float*)d_in[9];  const float* be  = (const float*)d_in[10];
    const float* Woe  = (const float*)d_in[11]; const float* boe = (const float*)d_in[12];
    const float* Won  = (const float*)d_in[13]; const float* bon = (const float*)d_in[14];
    const float* ln1g = (const float*)d_in[15]; const float* ln1b = (const float*)d_in[16];
    const float* ln3g = (const float*)d_in[17]; const float* ln3b = (const float*)d_in[18];
    const float* ln4g = (const float*)d_in[19]; const float* ln4b = (const float*)d_in[20];
    const float* ln5g = (const float*)d_in[21]; const float* ln5b = (const float*)d_in[22];
    const float* ln6g = (const float*)d_in[23]; const float* ln6b = (const float*)d_in[24];
    const float* m1W1 = (const float*)d_in[25]; const float* m1b1 = (const float*)d_in[26];
    const float* m1W2 = (const float*)d_in[27]; const float* m1b2 = (const float*)d_in[28];
    const float* m2W1 = (const float*)d_in[29]; const float* m2b1 = (const float*)d_in[30];
    const float* m2W2 = (const float*)d_in[31]; const float* m2b2 = (const float*)d_in[32];

    float* outx = (float*)d_out;
    float* outy = (float*)d_out + NB * NSEQ * DIMC;

    float* ws  = (float*)d_ws;
    float* X1  = ws;                    // 262144 floats each
    float* Q   = ws + 262144;
    float* K   = ws + 524288;
    float* V   = ws + 786432;
    short* wsS = (short*)(ws + 1048576);
    short* WeT  = wsS;                  //  65536 shorts (256x256)
    short* WoeT = wsS + 65536;          //  65536
    short* Wc   = wsS + 131072;         // 524288 shorts (16 chunks x 32768)
    short* ATTb = wsS + 655360;         // 33554432 shorts (67 MB)

    // weight prep
    k_transpose_bf16<<<dim3(8, 8),  256, 0, stream>>>(We,   WeT,  DIMC, DIMC);
    k_transpose_bf16<<<dim3(8, 8),  256, 0, stream>>>(Woe,  WoeT, DIMC, DIMC);
    k_prep_wc<<<16, 256, 0, stream>>>(m2W1, m2W2, Wc);

    k_ln_qkv<<<NB * NSEQ, 256, 0, stream>>>(x, ln1g, ln1b, Wq, bq, Wk, bk, Wv, bv, X1, Q, K, V);
    k_e_attn_m<<<EROWS / 64, 256, 0, stream>>>(y, WeT, be, Q, K, ATTb);
    k_edge_m<<<EROWS / 64, 256, 0, stream>>>(ATTb, WoeT, boe, outy);
    k_node_x<<<NB * NSEQ, 256, 0, stream>>>(ATTb, V, X1, Won, bon, ln3g, ln3b,
                                            m1W1, m1b1, m1W2, m1b2, ln5g, ln5b, outx);
    k_mlp_y6<<<EROWS / 128, 256, 0, stream>>>(outy, y, ln4g, ln4b,
                                              Wc, m2b1, m2b2, ln6g, ln6b);
}

// Round 5
// 972.676 us; speedup vs baseline: 1.1073x; 1.1073x over previous
//
#include <hip/hip_runtime.h>
#include <hip/hip_bf16.h>

// ---------------------------------------------------------------------------
// Encoder block. B=8, N=128, DIM=256, HEADS=8, dk=32, HID=1024.
// R8: k_mlp_y7 = 4-wave block, 80 KiB LDS -> 2 blocks/CU (2 waves/SIMD,
// TLP restored) while keeping the 512-reg/wave ceiling headroom (204 VGPR,
// no spill). Weight chunk split into W1/W2 32KB halves, ping-pong staged
// via global_load_lds: stage W2(h) || GEMM1(h); stage W1(h+1) || GEMM2(h).
// 2 barriers/chunk, each covering ~2048 CU-cycles of MFMA.
// ---------------------------------------------------------------------------

#define DIMC 256
#define NSEQ 128
#define NB 8
#define HID 1024
#define EROWS (NB * NSEQ * NSEQ)   // 131072

typedef __attribute__((ext_vector_type(8)))  short short8;
typedef __attribute__((ext_vector_type(16))) float f32x16;
typedef __attribute__((ext_vector_type(4)))  float f32x4;

__device__ __forceinline__ short f2bf(float f) {
    union { float f; unsigned u; } v; v.f = f;
    unsigned r = (v.u + 0x7FFF + ((v.u >> 16) & 1)) >> 16;
    return (short)r;
}
__device__ __forceinline__ float bf2f(short s) {
    union { unsigned u; float f; } v; v.u = ((unsigned)(unsigned short)s) << 16;
    return v.f;
}

__device__ __forceinline__ float wave_sum(float v) {
    #pragma unroll
    for (int o = 32; o; o >>= 1) v += __shfl_xor(v, o, 64);
    return v;
}

__device__ __forceinline__ float block_reduce_sum(float v, float* sc, int t) {
    #pragma unroll
    for (int o = 32; o > 0; o >>= 1) v += __shfl_down(v, o, 64);
    __syncthreads();
    if ((t & 63) == 0) sc[t >> 6] = v;
    __syncthreads();
    return sc[0] + sc[1] + sc[2] + sc[3];
}

// ---------------------------------------------------------------------------
// Kernel 1: x1 = LN1(x); q/k/v = x1 @ W{q,k,v} + b.  One block per (b,i) row.
// ---------------------------------------------------------------------------
__global__ __launch_bounds__(256, 2) void k_ln_qkv(
    const float* __restrict__ X, const float* __restrict__ g, const float* __restrict__ be,
    const float* __restrict__ Wq, const float* __restrict__ bq,
    const float* __restrict__ Wk, const float* __restrict__ bk,
    const float* __restrict__ Wv, const float* __restrict__ bv,
    float* __restrict__ X1, float* __restrict__ Q, float* __restrict__ K, float* __restrict__ V)
{
    __shared__ float xs[DIMC];
    __shared__ float red[4];
    const int t = threadIdx.x;
    const int row = blockIdx.x;
    float v = X[(size_t)row * DIMC + t];
    float mu = block_reduce_sum(v, red, t) * (1.f / DIMC);
    float d = v - mu;
    float var = block_reduce_sum(d * d, red, t) * (1.f / DIMC);
    float x1v = d * rsqrtf(var + 1e-5f) * g[t] + be[t];
    xs[t] = x1v;
    X1[(size_t)row * DIMC + t] = x1v;
    __syncthreads();
    float aq = bq[t], ak = bk[t], av = bv[t];
    #pragma unroll 4
    for (int k2 = 0; k2 < DIMC; ++k2) {
        float xv = xs[k2];
        aq = fmaf(xv, Wq[k2 * DIMC + t], aq);
        ak = fmaf(xv, Wk[k2 * DIMC + t], ak);
        av = fmaf(xv, Wv[k2 * DIMC + t], av);
    }
    Q[(size_t)row * DIMC + t] = aq;
    K[(size_t)row * DIMC + t] = ak;
    V[(size_t)row * DIMC + t] = av;
}

// ---------------------------------------------------------------------------
// Transpose + fp32->bf16 convert: dst[N][M] = bf16(src[M][N]).
// ---------------------------------------------------------------------------
__global__ __launch_bounds__(256) void k_transpose_bf16(
    const float* __restrict__ src, short* __restrict__ dst, int M, int N)
{
    __shared__ short tile[32][33];
    const int t = threadIdx.x, tx = t & 31, ty = t >> 5;
    const int bx = blockIdx.x, by = blockIdx.y;
    #pragma unroll
    for (int r = ty; r < 32; r += 8)
        tile[r][tx] = f2bf(src[(size_t)(by * 32 + r) * N + bx * 32 + tx]);
    __syncthreads();
    #pragma unroll
    for (int r = ty; r < 32; r += 8)
        dst[(size_t)(bx * 32 + r) * M + by * 32 + tx] = tile[tx][r];
}

// ---------------------------------------------------------------------------
// k_prep_wc: pack m2_W1/m2_W2 into chunk-major, swizzled bf16 layout.
// Per chunk h (0..15), 32768 shorts (64 KB):
//   [0..16384):  W1 part, [hh 0..63][k 0..255]
//   [16384..):   W2 part, [c 0..255][kk 0..63]
// ---------------------------------------------------------------------------
__global__ __launch_bounds__(256) void k_prep_wc(
    const float* __restrict__ W1, const float* __restrict__ W2, short* __restrict__ Wc)
{
    const int h = blockIdx.x, t = threadIdx.x;
    short* dst = Wc + (size_t)h * 32768;
    const int hh = t & 63, kq = t >> 6;
    for (int k0 = 0; k0 < 256; k0 += 4) {
        const int k = k0 + kq;
        float v = W1[(size_t)k * HID + h * 64 + hh];
        dst[hh * 256 + (((k >> 3) ^ (hh & 7)) << 3) + (k & 7)] = f2bf(v);
    }
    short* dst2 = dst + 16384;
    for (int kk = 0; kk < 64; ++kk) {
        float v = W2[(size_t)(h * 64 + kk) * DIMC + t];
        dst2[t * 64 + (((kk >> 3) ^ (t & 7)) << 3) + (kk & 7)] = f2bf(v);
    }
}

// ---------------------------------------------------------------------------
// k_e_attn_m: e = Y @ We + be (bf16 MFMA, 64 rows x 256 cols per block);
// epilogue: attn = (q*k/sqrt(32))*(e+1)*e -> ATTb (bf16).
// ---------------------------------------------------------------------------
__global__ __launch_bounds__(256, 2) void k_e_attn_m(
    const float* __restrict__ Y, const short* __restrict__ WeT,
    const float* __restrict__ be,
    const float* __restrict__ Q, const float* __restrict__ Kp,
    short* __restrict__ ATTb)
{
    __shared__ __align__(16) short As[64][256];
    const int t = threadIdx.x, w = t >> 6, lane = t & 63;
    const int l31 = lane & 31, kg = lane >> 5;
    const size_t R0 = (size_t)blockIdx.x * 64;

    for (int r = w * 16; r < w * 16 + 16; ++r) {
        float4 y4 = *(const float4*)&Y[(R0 + r) * DIMC + lane * 4];
        short4 s4;
        s4.x = f2bf(y4.x); s4.y = f2bf(y4.y); s4.z = f2bf(y4.z); s4.w = f2bf(y4.w);
        *(short4*)&As[r][(((lane >> 1) ^ (r & 7)) << 3) + (lane & 1) * 4] = s4;
    }
    __syncthreads();

    const int rh = (w & 1) * 32, cbase = (w >> 1) * 128;
    const int sw = l31 & 7;
    f32x16 acc[4];
    #pragma unroll
    for (int a = 0; a < 4; ++a)
        #pragma unroll
        for (int i = 0; i < 16; ++i) acc[a][i] = 0.f;

    #pragma unroll
    for (int ks = 0; ks < 16; ++ks) {
        const int gk = 2 * ks + kg;
        short8 a = *(const short8*)&As[rh + l31][(gk ^ sw) * 8];
        #pragma unroll
        for (int tt = 0; tt < 4; ++tt) {
            short8 b = *(const short8*)&WeT[(size_t)(cbase + tt * 32 + l31) * DIMC + gk * 8];
            acc[tt] = __builtin_amdgcn_mfma_f32_32x32x16_bf16(a, b, acc[tt], 0, 0, 0);
        }
    }

    const int m0 = (int)(R0);
    const int qrow = m0 >> 7, bidx = m0 >> 14, jb = m0 & 127;
    const float isq = 0.17677669529663687f;   // 1/sqrt(32)
    #pragma unroll
    for (int tt = 0; tt < 4; ++tt) {
        const int n = cbase + tt * 32 + l31;
        const float qv = Q[(size_t)qrow * DIMC + n];
        const float bb = be[n];
        #pragma unroll
        for (int i = 0; i < 16; ++i) {
            const int row = rh + 4 * kg + (i & 3) + 8 * (i >> 2);
            const float kv = Kp[(size_t)((bidx << 7) + jb + row) * DIMC + n];
            const float e = acc[tt][i] + bb;
            const float qk = qv * kv * isq;
            ATTb[(size_t)(m0 + row) * DIMC + n] = f2bf(qk * (e + 1.f) * e);
        }
    }
}

// ---------------------------------------------------------------------------
// k_edge_m: edge = ATTb @ Woe + boe (bf16 MFMA) -> EY fp32 (d_out y-region).
// ---------------------------------------------------------------------------
__global__ __launch_bounds__(256, 2) void k_edge_m(
    const short* __restrict__ ATTb, const short* __restrict__ WoeT,
    const float* __restrict__ boe, float* __restrict__ EDGE)
{
    __shared__ __align__(16) short As[64][256];
    const int t = threadIdx.x, w = t >> 6, lane = t & 63;
    const int l31 = lane & 31, kg = lane >> 5;
    const size_t R0 = (size_t)blockIdx.x * 64;

    #pragma unroll
    for (int it = 0; it < 8; ++it) {
        const int r = w * 16 + it * 2 + kg;
        short8 v = *(const short8*)&ATTb[(R0 + r) * DIMC + l31 * 8];
        *(short8*)&As[r][((l31 ^ (r & 7))) * 8] = v;
    }
    __syncthreads();

    const int rh = (w & 1) * 32, cbase = (w >> 1) * 128;
    const int sw = l31 & 7;
    f32x16 acc[4];
    #pragma unroll
    for (int a = 0; a < 4; ++a)
        #pragma unroll
        for (int i = 0; i < 16; ++i) acc[a][i] = 0.f;

    #pragma unroll
    for (int ks = 0; ks < 16; ++ks) {
        const int gk = 2 * ks + kg;
        short8 a = *(const short8*)&As[rh + l31][(gk ^ sw) * 8];
        #pragma unroll
        for (int tt = 0; tt < 4; ++tt) {
            short8 b = *(const short8*)&WoeT[(size_t)(cbase + tt * 32 + l31) * DIMC + gk * 8];
            acc[tt] = __builtin_amdgcn_mfma_f32_32x32x16_bf16(a, b, acc[tt], 0, 0, 0);
        }
    }

    const int m0 = (int)(R0);
    #pragma unroll
    for (int tt = 0; tt < 4; ++tt) {
        const int n = cbase + tt * 32 + l31;
        const float bb = boe[n];
        #pragma unroll
        for (int i = 0; i < 16; ++i) {
            const int row = rh + 4 * kg + (i & 3) + 8 * (i >> 2);
            EDGE[(size_t)(m0 + row) * DIMC + n] = acc[tt][i] + bb;
        }
    }
}

// ---------------------------------------------------------------------------
// Kernel 4: x-path tail. ATT bf16. Max-free softmax (logits tiny, exp safe).
// ---------------------------------------------------------------------------
__global__ __launch_bounds__(256, 2) void k_node_x(
    const short* __restrict__ ATTb, const float* __restrict__ V,
    const float* __restrict__ X1,
    const float* __restrict__ Won, const float* __restrict__ bon,
    const float* __restrict__ g3, const float* __restrict__ b3,
    const float* __restrict__ W1, const float* __restrict__ b1,
    const float* __restrict__ W2, const float* __restrict__ b2,
    const float* __restrict__ g5, const float* __restrict__ b5,
    float* __restrict__ OUTX)
{
    __shared__ float ns[DIMC];
    __shared__ float x2s[DIMC];
    __shared__ float hs[HID];
    __shared__ float red[4];
    const int t = threadIdx.x;
    const int bi = blockIdx.x;
    const int b = bi >> 7;
    const short* arow = ATTb + (size_t)bi * NSEQ * DIMC + t;
    const float* vbase = V + (size_t)b * NSEQ * DIMC + t;
    float l = 0.f, acc = 0.f;
    #pragma unroll 4
    for (int j = 0; j < NSEQ; ++j) {
        float a = bf2f(arow[(size_t)j * DIMC]);
        float vv = vbase[(size_t)j * DIMC];
        float p = __expf(a);
        l += p;
        acc = fmaf(p, vv, acc);
    }
    ns[t] = acc / l;
    __syncthreads();
    float o = bon[t];
    #pragma unroll 4
    for (int k2 = 0; k2 < DIMC; ++k2) o = fmaf(ns[k2], Won[k2 * DIMC + t], o);
    float resid = X1[(size_t)bi * DIMC + t] + o;
    float mu = block_reduce_sum(resid, red, t) * (1.f / DIMC);
    float d = resid - mu;
    float var = block_reduce_sum(d * d, red, t) * (1.f / DIMC);
    float x2 = d * rsqrtf(var + 1e-5f) * g3[t] + b3[t];
    x2s[t] = x2;
    __syncthreads();
    float4 h = *(const float4*)&b1[t * 4];
    for (int k2 = 0; k2 < DIMC; ++k2) {
        float xv = x2s[k2];
        float4 w = *(const float4*)&W1[(size_t)k2 * HID + t * 4];
        h.x = fmaf(xv, w.x, h.x); h.y = fmaf(xv, w.y, h.y);
        h.z = fmaf(xv, w.z, h.z); h.w = fmaf(xv, w.w, h.w);
    }
    h.x = fmaxf(h.x, 0.f); h.y = fmaxf(h.y, 0.f); h.z = fmaxf(h.z, 0.f); h.w = fmaxf(h.w, 0.f);
    *(float4*)&hs[t * 4] = h;
    __syncthreads();
    float o2 = b2[t];
    #pragma unroll 4
    for (int hh = 0; hh < HID; ++hh) o2 = fmaf(hs[hh], W2[(size_t)hh * DIMC + t], o2);
    float r2 = x2 + o2;
    float mu2 = block_reduce_sum(r2, red, t) * (1.f / DIMC);
    float d2 = r2 - mu2;
    float v2 = block_reduce_sum(d2 * d2, red, t) * (1.f / DIMC);
    OUTX[(size_t)bi * DIMC + t] = d2 * rsqrtf(v2 + 1e-5f) * g5[t] + b5[t];
}

// ---------------------------------------------------------------------------
// Kernel 5 (R8): k_mlp_y7 — fused y-path tail.
// 128 rows/block, 4 waves x 32 rows, 32x32x16 bf16 MFMA, 256 threads.
// LDS 80 KiB (2x32K W-halves ping-pong + 16K Hscr) -> 2 blocks/CU.
// Schedule per chunk h: {stage W2(h)->B1 | GEMM1 from B0} barrier
//                       {stage W1(h+1)->B0 | GEMM2 from B1} barrier.
// ---------------------------------------------------------------------------
__global__ __launch_bounds__(256, 2) void k_mlp_y7(
    float* __restrict__ EY, const float* __restrict__ Y,
    const float* __restrict__ g4, const float* __restrict__ b4,
    const short* __restrict__ Wc, const float* __restrict__ b1v,
    const float* __restrict__ b2v,
    const float* __restrict__ g6, const float* __restrict__ b6)
{
    __shared__ __align__(16) short Hbuf[2][16384];   // 2 x 32 KB W-half buffers
    __shared__ __align__(16) short Hscr[4][32][64];  // 16 KB hidden scratch
    const int t = threadIdx.x;
    const int w = t >> 6, lane = t & 63;
    const int l31 = lane & 31, kg = lane >> 5;
    const int r7 = l31 & 7;
    const size_t R0 = (size_t)blockIdx.x * 128;
    short* Wb = &Hbuf[0][0];   // 32768 shorts contiguous = 128 rows x 256 (y2 staging)

    // --- Phase A: y2 = LN4(EY + Y), rows w*32..w*32+31 -> Wb (bf16, swizzled)
    {
        const float4 gv = *(const float4*)&g4[lane * 4];
        const float4 bv = *(const float4*)&b4[lane * 4];
        const int gw = lane >> 1;
        for (int rr = 0; rr < 32; ++rr) {
            const int row = w * 32 + rr;
            const float4 e4 = *(const float4*)&EY[(R0 + row) * DIMC + lane * 4];
            const float4 y4v = *(const float4*)&Y[(R0 + row) * DIMC + lane * 4];
            float v0 = e4.x + y4v.x, v1 = e4.y + y4v.y, v2 = e4.z + y4v.z, v3 = e4.w + y4v.w;
            float mu = wave_sum(v0 + v1 + v2 + v3) * (1.f / DIMC);
            float d0 = v0 - mu, d1 = v1 - mu, d2 = v2 - mu, d3 = v3 - mu;
            float var = wave_sum(d0 * d0 + d1 * d1 + d2 * d2 + d3 * d3) * (1.f / DIMC);
            float rs = rsqrtf(var + 1e-5f);
            short4 s4;
            s4.x = f2bf(d0 * rs * gv.x + bv.x);
            s4.y = f2bf(d1 * rs * gv.y + bv.y);
            s4.z = f2bf(d2 * rs * gv.z + bv.z);
            s4.w = f2bf(d3 * rs * gv.w + bv.w);
            *(short4*)&Wb[row * 256 + ((gw ^ (rr & 7)) << 3) + (lane & 1) * 4] = s4;
        }
    }
    // --- A-fragments: wave's 32 rows x K=256 (wave-local write->read)
    short8 af[16];
    {
        const int row = w * 32 + l31;      // row & 7 == r7
        #pragma unroll
        for (int s = 0; s < 16; ++s)
            af[s] = *(const short8*)&Wb[row * 256 + (((2 * s + kg) ^ r7) << 3)];
    }
    __syncthreads();   // all waves done reading y2 before staging overwrites it

    // --- stage helpers: 32 KB halves via global_load_lds (256 thr x 8 x 16B)
    auto stageW1 = [&](int h) {
        const char* src = (const char*)Wc + (size_t)h * 65536 + t * 16;
        char* dstb = (char*)&Hbuf[0][0] + t * 16;
        #pragma unroll
        for (int p = 0; p < 8; ++p) {
            __builtin_amdgcn_global_load_lds(
                (const __attribute__((address_space(1))) unsigned*)(src + p * 4096),
                (__attribute__((address_space(3))) unsigned*)(dstb + p * 4096),
                16, 0, 0);
        }
    };
    auto stageW2 = [&](int h) {
        const char* src = (const char*)Wc + (size_t)h * 65536 + 32768 + t * 16;
        char* dstb = (char*)&Hbuf[1][0] + t * 16;
        #pragma unroll
        for (int p = 0; p < 8; ++p) {
            __builtin_amdgcn_global_load_lds(
                (const __attribute__((address_space(1))) unsigned*)(src + p * 4096),
                (__attribute__((address_space(3))) unsigned*)(dstb + p * 4096),
                16, 0, 0);
        }
    };

    stageW1(0);
    __syncthreads();   // W1(0) resident

    f32x16 acc[8];
    #pragma unroll
    for (int a = 0; a < 8; ++a)
        #pragma unroll
        for (int i = 0; i < 16; ++i) acc[a][i] = 0.f;

    for (int h = 0; h < 16; ++h) {
        // ---- phase 1: stage W2(h) in flight; GEMM1 from Hbuf[0] (W1(h)) ----
        stageW2(h);
        const float bb0 = b1v[h * 64 + l31];
        const float bb1 = b1v[h * 64 + 32 + l31];
        f32x16 c1[2];
        #pragma unroll
        for (int a = 0; a < 2; ++a)
            #pragma unroll
            for (int i = 0; i < 16; ++i) c1[a][i] = 0.f;
        #pragma unroll
        for (int s = 0; s < 16; ++s) {
            const int g = ((2 * s + kg) ^ r7) << 3;
            #pragma unroll
            for (int tt = 0; tt < 2; ++tt) {
                short8 b = *(const short8*)&Hbuf[0][(tt * 32 + l31) * 256 + g];
                c1[tt] = __builtin_amdgcn_mfma_f32_32x32x16_bf16(af[s], b, c1[tt], 0, 0, 0);
            }
        }
        // relu + bias -> per-wave H scratch
        #pragma unroll
        for (int tt = 0; tt < 2; ++tt) {
            const int cq = tt * 4 + (l31 >> 3), c7 = l31 & 7;
            const float bb = tt ? bb1 : bb0;
            #pragma unroll
            for (int i = 0; i < 16; ++i) {
                const int row = 4 * kg + (i & 3) + 8 * (i >> 2);
                Hscr[w][row][((cq ^ (row & 7)) << 3) + c7] =
                    f2bf(fmaxf(c1[tt][i] + bb, 0.f));
            }
        }
        __syncthreads();   // W2(h) landed; all waves done with Hbuf[0]

        // ---- phase 2: stage W1(h+1) in flight; GEMM2 from Hbuf[1] (W2(h)) ----
        if (h < 15) stageW1(h + 1);
        #pragma unroll
        for (int s = 0; s < 4; ++s) {
            const int g2 = ((2 * s + kg) ^ r7) << 3;
            short8 hf = *(const short8*)&Hscr[w][l31][g2];
            #pragma unroll
            for (int ct = 0; ct < 8; ++ct) {
                short8 b = *(const short8*)&Hbuf[1][(ct * 32 + l31) * 64 + g2];
                acc[ct] = __builtin_amdgcn_mfma_f32_32x32x16_bf16(hf, b, acc[ct], 0, 0, 0);
            }
        }
        __syncthreads();   // W1(h+1) landed; all waves done with Hbuf[1]
    }

    // --- Epilogue ---
    // re-materialize y2 (wave-local rows) into Wb for C-frag-layout residual read
    {
        const int row = w * 32 + l31;
        #pragma unroll
        for (int s = 0; s < 16; ++s)
            *(short8*)&Wb[row * 256 + (((2 * s + kg) ^ r7) << 3)] = af[s];
    }
    // residual + bias into acc (wave-local rows only)
    #pragma unroll
    for (int ct = 0; ct < 8; ++ct) {
        const int col = ct * 32 + l31;
        const float bb = b2v[col];
        const int cq = col >> 3, c7 = col & 7;
        #pragma unroll
        for (int i = 0; i < 16; ++i) {
            const int row = 4 * kg + (i & 3) + 8 * (i >> 2);
            short yv = Wb[(w * 32 + row) * 256 + ((cq ^ (row & 7)) << 3) + c7];
            acc[ct][i] += bb + bf2f(yv);
        }
    }
    // LN6: per-row reduce over 8 col-tiles then 32 lanes (kg halves independent)
    float mus[16], rss[16];
    #pragma unroll
    for (int i = 0; i < 16; ++i) {
        float s = 0.f;
        #pragma unroll
        for (int ct = 0; ct < 8; ++ct) s += acc[ct][i];
        #pragma unroll
        for (int m = 1; m < 32; m <<= 1) s += __shfl_xor(s, m, 64);
        mus[i] = s * (1.f / DIMC);
    }
    #pragma unroll
    for (int i = 0; i < 16; ++i) {
        float v = 0.f;
        #pragma unroll
        for (int ct = 0; ct < 8; ++ct) { float d = acc[ct][i] - mus[i]; v += d * d; }
        #pragma unroll
        for (int m = 1; m < 32; m <<= 1) v += __shfl_xor(v, m, 64);
        rss[i] = rsqrtf(v * (1.f / DIMC) + 1e-5f);
    }
    #pragma unroll
    for (int ct = 0; ct < 8; ++ct) {
        const int col = ct * 32 + l31;
        const float gg = g6[col], bo = b6[col];
        #pragma unroll
        for (int i = 0; i < 16; ++i) {
            const int row = 4 * kg + (i & 3) + 8 * (i >> 2);
            EY[(R0 + w * 32 + row) * DIMC + col] = (acc[ct][i] - mus[i]) * rss[i] * gg + bo;
        }
    }
}

// ---------------------------------------------------------------------------
extern "C" void kernel_launch(void* const* d_in, const int* in_sizes, int n_in,
                              void* d_out, int out_size, void* d_ws, size_t ws_size,
                              hipStream_t stream) {
    const float* x    = (const float*)d_in[0];
    const float* y    = (const float*)d_in[1];
    const float* Wq   = (const float*)d_in[3];  const float* bq  = (const float*)d_in[4];
    const float* Wk   = (const float*)d_in[5];  const float* bk  = (const float*)d_in[6];
    const float* Wv   = (const float*)d_in[7];  const float* bv  = (const float*)d_in[8];
    const float* We   = (const float*)d_in[9];  const float* be  = (const float*)d_in[10];
    const float* Woe  = (const float*)d_in[11]; const float* boe = (const float*)d_in[12];
    const float* Won  = (const float*)d_in[13]; const float* bon = (const float*)d_in[14];
    const float* ln1g = (const float*)d_in[15]; const float* ln1b = (const float*)d_in[16];
    const float* ln3g = (const float*)d_in[17]; const float* ln3b = (const float*)d_in[18];
    const float* ln4g = (const float*)d_in[19]; const float* ln4b = (const float*)d_in[20];
    const float* ln5g = (const float*)d_in[21]; const float* ln5b = (const float*)d_in[22];
    const float* ln6g = (const float*)d_in[23]; const float* ln6b = (const float*)d_in[24];
    const float* m1W1 = (const float*)d_in[25]; const float* m1b1 = (const float*)d_in[26];
    const float* m1W2 = (const float*)d_in[27]; const float* m1b2 = (const float*)d_in[28];
    const float* m2W1 = (const float*)d_in[29]; const float* m2b1 = (const float*)d_in[30];
    const float* m2W2 = (const float*)d_in[31]; const float* m2b2 = (const float*)d_in[32];

    float* outx = (float*)d_out;
    float* outy = (float*)d_out + NB * NSEQ * DIMC;

    float* ws  = (float*)d_ws;
    float* X1  = ws;                    // 262144 floats each
    float* Q   = ws + 262144;
    float* K   = ws + 524288;
    float* V   = ws + 786432;
    short* wsS = (short*)(ws + 1048576);
    short* WeT  = wsS;                  //  65536 shorts (256x256)
    short* WoeT = wsS + 65536;          //  65536
    short* Wc   = wsS + 131072;         // 524288 shorts (16 chunks x 32768)
    short* ATTb = wsS + 655360;         // 33554432 shorts (67 MB)

    // weight prep
    k_transpose_bf16<<<dim3(8, 8),  256, 0, stream>>>(We,   WeT,  DIMC, DIMC);
    k_transpose_bf16<<<dim3(8, 8),  256, 0, stream>>>(Woe,  WoeT, DIMC, DIMC);
    k_prep_wc<<<16, 256, 0, stream>>>(m2W1, m2W2, Wc);

    k_ln_qkv<<<NB * NSEQ, 256, 0, stream>>>(x, ln1g, ln1b, Wq, bq, Wk, bk, Wv, bv, X1, Q, K, V);
    k_e_attn_m<<<EROWS / 64, 256, 0, stream>>>(y, WeT, be, Q, K, ATTb);
    k_edge_m<<<EROWS / 64, 256, 0, stream>>>(ATTb, WoeT, boe, outy);
    k_node_x<<<NB * NSEQ, 256, 0, stream>>>(ATTb, V, X1, Won, bon, ln3g, ln3b,
                                            m1W1, m1b1, m1W2, m1b2, ln5g, ln5b, outx);
    k_mlp_y7<<<EROWS / 128, 256, 0, stream>>>(outy, y, ln4g, ln4b,
                                              Wc, m2b1, m2b2, ln6g, ln6b);
}